// Round 1
// baseline (31532.843 us; speedup 1.0000x reference)
//
#include <hip/hip_runtime.h>

// LSTM_38869454028951: B=512, T=365, F=16, H=256, 2 layers + linear head.
// Strategy: batch-parallel persistent kernel. 32 WGs x 1024 threads; each WG
// owns 16 batch rows and runs all 365 timesteps (both layers fused).
// Precision: bf16 hi/lo split MFMA (3 terms, fp32 accum) ~ fp32 accuracy.

#define T_STEPS 365
#define HSTR 520   // h12 LDS row stride in bf16 elems (1040B: 16B-aligned rows, word stride 260 % 32 == 4 -> 2-way alias only)
#define XSTR 40    // xs LDS row stride (80B aligned)

typedef __attribute__((ext_vector_type(8))) short short8;
typedef __attribute__((ext_vector_type(4))) float float4_;

#define MFMA16(a, b, c) __builtin_amdgcn_mfma_f32_16x16x32_bf16((a), (b), (c), 0, 0, 0)

__device__ __forceinline__ unsigned short f2bf(float v) {
    union { float f; unsigned int u; } a; a.f = v;
    unsigned int r = a.u + 0x7fffu + ((a.u >> 16) & 1u);  // RNE
    return (unsigned short)(r >> 16);
}
__device__ __forceinline__ float bf2f(unsigned short h) {
    union { unsigned int u; float f; } a; a.u = ((unsigned int)h) << 16; return a.f;
}
__device__ __forceinline__ float sigm(float x)  { return 1.f / (1.f + __expf(-x)); }
__device__ __forceinline__ float tanh_(float x) { return 2.f / (1.f + __expf(-2.f * x)) - 1.f; }

// ---------------- prep: split fp32 weights into bf16 hi/lo arrays in ws ----------------
__global__ void lstm_prep(
    const float* __restrict__ Wih1, const float* __restrict__ Whh1,
    const float* __restrict__ bih1, const float* __restrict__ bhh1,
    const float* __restrict__ Wih2, const float* __restrict__ Whh2,
    const float* __restrict__ bih2, const float* __restrict__ bhh2,
    unsigned short* __restrict__ w1r_hi, unsigned short* __restrict__ w1r_lo,
    unsigned short* __restrict__ w1x_hi, unsigned short* __restrict__ w1x_lo,
    unsigned short* __restrict__ w2_hi,  unsigned short* __restrict__ w2_lo,
    float* __restrict__ bias1, float* __restrict__ bias2)
{
    const int n = blockIdx.x;      // 0..1023 gate-row
    const int tid = threadIdx.x;   // 256 threads

    // recurrent layer-1 weights: [1024][256]
    {
        int k = tid;
        float v = Whh1[n * 256 + k];
        unsigned short h = f2bf(v);
        w1r_hi[n * 256 + k] = h;
        w1r_lo[n * 256 + k] = f2bf(v - bf2f(h));
    }
    // input layer-1 weights, K padded 16->32: [1024][32]
    if (tid < 32) {
        float v = (tid < 16) ? Wih1[n * 16 + tid] : 0.f;
        unsigned short h = f2bf(v);
        w1x_hi[n * 32 + tid] = h;
        w1x_lo[n * 32 + tid] = f2bf(v - bf2f(h));
    }
    // layer-2 combined [Wih2 | Whh2]: [1024][512]
    for (int k = tid; k < 512; k += 256) {
        float v = (k < 256) ? Wih2[n * 256 + k] : Whh2[n * 256 + (k - 256)];
        unsigned short h = f2bf(v);
        w2_hi[n * 512 + k] = h;
        w2_lo[n * 512 + k] = f2bf(v - bf2f(h));
    }
    if (tid == 0) {
        bias1[n] = bih1[n] + bhh1[n];
        bias2[n] = bih2[n] + bhh2[n];
    }
}

// ---------------- main persistent fused 2-layer LSTM ----------------
__global__ __launch_bounds__(1024) void lstm_fused(
    const float* __restrict__ x,
    const unsigned short* __restrict__ w1r_hi, const unsigned short* __restrict__ w1r_lo,
    const unsigned short* __restrict__ w1x_hi, const unsigned short* __restrict__ w1x_lo,
    const unsigned short* __restrict__ w2_hi,  const unsigned short* __restrict__ w2_lo,
    const float* __restrict__ bias1, const float* __restrict__ bias2,
    const float* __restrict__ Wlin, const float* __restrict__ blin,
    float* __restrict__ out)
{
    // h state for both layers, bf16 hi/lo split. cols 0:256 = h1, 256:512 = h2.
    __shared__ unsigned short h12_hi[16][HSTR];
    __shared__ unsigned short h12_lo[16][HSTR];
    __shared__ unsigned short xs_hi[16][XSTR];
    __shared__ unsigned short xs_lo[16][XSTR];
    __shared__ float h2f[16][260];   // final-layer h in fp32 for the head

    const int tid  = threadIdx.x;
    const int wv   = tid >> 6;       // 16 waves
    const int lane = tid & 63;
    const int quad = lane >> 4;
    const int r16  = lane & 15;
    const int b0   = blockIdx.x * 16;   // batch base, 32 WGs x 16 = 512

    // zero-init LDS (h=0, x pad cols stay 0)
    for (int i = tid; i < 16 * HSTR; i += 1024) { (&h12_hi[0][0])[i] = 0; (&h12_lo[0][0])[i] = 0; }
    for (int i = tid; i < 16 * XSTR; i += 1024) { (&xs_hi[0][0])[i]  = 0; (&xs_lo[0][0])[i]  = 0; }

    float c1s[4] = {0.f, 0.f, 0.f, 0.f};
    float c2s[4] = {0.f, 0.f, 0.f, 0.f};

    const int colw = 16 * wv + r16;       // hidden column this lane owns in updates
    int wrow[4];
    float b1v[4], b2v[4];
#pragma unroll
    for (int g = 0; g < 4; g++) {
        wrow[g] = g * 256 + colw;         // gate-row for B fragments
        b1v[g] = bias1[wrow[g]];
        b2v[g] = bias2[wrow[g]];
    }

    __syncthreads();

    for (int t = 0; t < T_STEPS; t++) {
        // ---- stage x_t (16 batch x 16 feats), split to bf16 hi/lo ----
        if (tid < 256) {
            int bb = tid >> 4, k = tid & 15;
            float v = x[((b0 + bb) * T_STEPS + t) * 16 + k];
            unsigned short h = f2bf(v);
            xs_hi[bb][k] = h;
            xs_lo[bb][k] = f2bf(v - bf2f(h));
        }
        __syncthreads();   // A: xs visible, prev updates visible

        // ---- layer-1 GEMM: z1 = h1 @ Whh1^T + x @ Wih1^T + b1 ----
        float4_ acc[4];
#pragma unroll
        for (int g = 0; g < 4; g++) { float bv = b1v[g]; acc[g] = (float4_){bv, bv, bv, bv}; }

        for (int ks = 0; ks < 8; ks++) {
            const int ko = ks * 32 + quad * 8;
            short8 a_hi = *(const short8*)&h12_hi[r16][ko];
            short8 a_lo = *(const short8*)&h12_lo[r16][ko];
#pragma unroll
            for (int g = 0; g < 4; g++) {
                const unsigned short* bp = w1r_hi + wrow[g] * 256 + ko;
                const unsigned short* bq = w1r_lo + wrow[g] * 256 + ko;
                short8 b_hi = *(const short8*)bp;
                short8 b_lo = *(const short8*)bq;
                acc[g] = MFMA16(a_hi, b_hi, acc[g]);
                acc[g] = MFMA16(a_lo, b_hi, acc[g]);
                acc[g] = MFMA16(a_hi, b_lo, acc[g]);
            }
        }
        {   // x contribution (single K=32 block, upper 16 k's are zero pad)
            const int ko = quad * 8;
            short8 a_hi = *(const short8*)&xs_hi[r16][ko];
            short8 a_lo = *(const short8*)&xs_lo[r16][ko];
#pragma unroll
            for (int g = 0; g < 4; g++) {
                const unsigned short* bp = w1x_hi + wrow[g] * 32 + ko;
                const unsigned short* bq = w1x_lo + wrow[g] * 32 + ko;
                short8 b_hi = *(const short8*)bp;
                short8 b_lo = *(const short8*)bq;
                acc[g] = MFMA16(a_hi, b_hi, acc[g]);
                acc[g] = MFMA16(a_lo, b_hi, acc[g]);
                acc[g] = MFMA16(a_hi, b_lo, acc[g]);
            }
        }
        __syncthreads();   // B: all GEMM reads of h1_{t-1} done

        // ---- layer-1 gate update. C/D layout: row(batch)=quad*4+r, col=lane&15 ----
#pragma unroll
        for (int rr = 0; rr < 4; rr++) {
            float zi = acc[0][rr], zf = acc[1][rr], zg = acc[2][rr], zo = acc[3][rr];
            float c = sigm(zf) * c1s[rr] + sigm(zi) * tanh_(zg);
            c1s[rr] = c;
            float h = sigm(zo) * tanh_(c);
            int bb = quad * 4 + rr;
            unsigned short hh = f2bf(h);
            h12_hi[bb][colw] = hh;
            h12_lo[bb][colw] = f2bf(h - bf2f(hh));
        }
        __syncthreads();   // C: h1_t visible

        // ---- layer-2 GEMM: z2 = [h1_t | h2_{t-1}] @ [Wih2|Whh2]^T + b2 (K=512) ----
#pragma unroll
        for (int g = 0; g < 4; g++) { float bv = b2v[g]; acc[g] = (float4_){bv, bv, bv, bv}; }

        for (int ks = 0; ks < 16; ks++) {
            const int ko = ks * 32 + quad * 8;
            short8 a_hi = *(const short8*)&h12_hi[r16][ko];
            short8 a_lo = *(const short8*)&h12_lo[r16][ko];
#pragma unroll
            for (int g = 0; g < 4; g++) {
                const unsigned short* bp = w2_hi + wrow[g] * 512 + ko;
                const unsigned short* bq = w2_lo + wrow[g] * 512 + ko;
                short8 b_hi = *(const short8*)bp;
                short8 b_lo = *(const short8*)bq;
                acc[g] = MFMA16(a_hi, b_hi, acc[g]);
                acc[g] = MFMA16(a_lo, b_hi, acc[g]);
                acc[g] = MFMA16(a_hi, b_lo, acc[g]);
            }
        }
        __syncthreads();   // D: all GEMM reads of h2_{t-1} done

        // ---- layer-2 gate update ----
#pragma unroll
        for (int rr = 0; rr < 4; rr++) {
            float zi = acc[0][rr], zf = acc[1][rr], zg = acc[2][rr], zo = acc[3][rr];
            float c = sigm(zf) * c2s[rr] + sigm(zi) * tanh_(zg);
            c2s[rr] = c;
            float h = sigm(zo) * tanh_(c);
            int bb = quad * 4 + rr;
            unsigned short hh = f2bf(h);
            h12_hi[bb][256 + colw] = hh;
            h12_lo[bb][256 + colw] = f2bf(h - bf2f(hh));
            h2f[bb][colw] = h;
        }
        // no barrier needed here: next iter's A barrier orders these writes
        // before any reader (next L2 GEMM is 3 barriers away).
    }
    __syncthreads();

    // ---- head: out[b] = h2_T[b] . Wlin + blin ; wave wv handles batch row wv ----
    float part = 0.f;
#pragma unroll
    for (int i = 0; i < 4; i++) {
        int k = lane + 64 * i;
        part += h2f[wv][k] * Wlin[k];
    }
    for (int s = 32; s > 0; s >>= 1) part += __shfl_down(part, s, 64);
    if (lane == 0) out[b0 + wv] = part + blin[0];
}

extern "C" void kernel_launch(void* const* d_in, const int* in_sizes, int n_in,
                              void* d_out, int out_size, void* d_ws, size_t ws_size,
                              hipStream_t stream) {
    const float* x     = (const float*)d_in[0];
    const float* Wih1  = (const float*)d_in[1];
    const float* Whh1  = (const float*)d_in[2];
    const float* bih1  = (const float*)d_in[3];
    const float* bhh1  = (const float*)d_in[4];
    const float* Wih2  = (const float*)d_in[5];
    const float* Whh2  = (const float*)d_in[6];
    const float* bih2  = (const float*)d_in[7];
    const float* bhh2  = (const float*)d_in[8];
    const float* Wlin  = (const float*)d_in[9];
    const float* blin  = (const float*)d_in[10];
    float* out = (float*)d_out;

    // workspace carve (all 16B-aligned sizes)
    char* p = (char*)d_ws;
    unsigned short* w1r_hi = (unsigned short*)p; p += 1024 * 256 * 2;
    unsigned short* w1r_lo = (unsigned short*)p; p += 1024 * 256 * 2;
    unsigned short* w1x_hi = (unsigned short*)p; p += 1024 * 32 * 2;
    unsigned short* w1x_lo = (unsigned short*)p; p += 1024 * 32 * 2;
    unsigned short* w2_hi  = (unsigned short*)p; p += 1024 * 512 * 2;
    unsigned short* w2_lo  = (unsigned short*)p; p += 1024 * 512 * 2;
    float* bias1 = (float*)p; p += 1024 * 4;
    float* bias2 = (float*)p; p += 1024 * 4;

    lstm_prep<<<1024, 256, 0, stream>>>(Wih1, Whh1, bih1, bhh1, Wih2, Whh2, bih2, bhh2,
                                        w1r_hi, w1r_lo, w1x_hi, w1x_lo, w2_hi, w2_lo,
                                        bias1, bias2);
    lstm_fused<<<32, 1024, 0, stream>>>(x, w1r_hi, w1r_lo, w1x_hi, w1x_lo, w2_hi, w2_lo,
                                        bias1, bias2, Wlin, blin, out);
}

// Round 2
// 11337.066 us; speedup vs baseline: 2.7814x; 2.7814x over previous
//
#include <hip/hip_runtime.h>

// LSTM_38869454028951: B=512, T=365, F=16, H=256, 2 layers + linear head.
// Round 2: all-CU decomposition. 16 batch groups (32 rows each) x 16 N-slices
// (16 hidden cols each) = 256 WGs x 512 threads, 1 WG/CU (LDS-bound).
// Per step: P1 (layer-1 GEMM K=288 incl. x) -> h1 publish -> bg barrier ->
// stage [h1_t | h2_{t-1}] to LDS -> P2 (layer-2 GEMM K=512) -> h2 publish ->
// bg barrier. Weights pre-blocked per (gate,slice) wave into contiguous 1KB
// K-chunks. Precision: bf16 hi/lo 3-term MFMA everywhere (round-1 absmax 0.0).

#define T_STEPS 365

typedef __attribute__((ext_vector_type(8))) short short8;
typedef __attribute__((ext_vector_type(8))) unsigned short ushort8;
typedef __attribute__((ext_vector_type(4))) float float4_;

#define MFMA16(a, b, c) __builtin_amdgcn_mfma_f32_16x16x32_bf16((a), (b), (c), 0, 0, 0)

__device__ __forceinline__ unsigned short f2bf(float v) {
    union { float f; unsigned int u; } a; a.f = v;
    unsigned int r = a.u + 0x7fffu + ((a.u >> 16) & 1u);  // RNE
    return (unsigned short)(r >> 16);
}
__device__ __forceinline__ float bf2f(unsigned short h) {
    union { unsigned int u; float f; } a; a.u = ((unsigned int)h) << 16; return a.f;
}
__device__ __forceinline__ float sigm(float x)  { return 1.f / (1.f + __expf(-x)); }
__device__ __forceinline__ float tanh_(float x) { return 2.f / (1.f + __expf(-2.f * x)) - 1.f; }

// ---------------- prep: blocked hi/lo weights + biases ----------------
// w1blk[hi/lo]: [64 tiles][9 ks][16 rows][32 k]  (tile = g*16 + ns)
//   ks<8: Whh1 k=ks*32+kk ; ks==8: kk<16 -> Wih1[.][kk], else 0
// w2blk[hi/lo]: [64][16][16][32]  k<256: Wih2, k>=256: Whh2[k-256]
__global__ void prep_w(
    const float* __restrict__ Wih1, const float* __restrict__ Whh1,
    const float* __restrict__ bih1, const float* __restrict__ bhh1,
    const float* __restrict__ Wih2, const float* __restrict__ Whh2,
    const float* __restrict__ bih2, const float* __restrict__ bhh2,
    unsigned short* __restrict__ w1h, unsigned short* __restrict__ w1l,
    unsigned short* __restrict__ w2h, unsigned short* __restrict__ w2l,
    float* __restrict__ bias1, float* __restrict__ bias2)
{
    const int tile = blockIdx.x;          // 64
    const int g = tile >> 4, ns = tile & 15;
    const int tid = threadIdx.x;          // 256

    for (int idx = tid; idx < 9 * 512; idx += 256) {
        int ks = idx >> 9, off = idx & 511, r = off >> 5, kk = off & 31;
        int R = g * 256 + ns * 16 + r;
        float v;
        if (ks < 8)      v = Whh1[R * 256 + ks * 32 + kk];
        else if (kk < 16) v = Wih1[R * 16 + kk];
        else             v = 0.f;
        unsigned short h = f2bf(v);
        size_t d = (size_t)(tile * 9 + ks) * 512 + off;
        w1h[d] = h; w1l[d] = f2bf(v - bf2f(h));
    }
    for (int idx = tid; idx < 16 * 512; idx += 256) {
        int ks = idx >> 9, off = idx & 511, r = off >> 5, kk = off & 31;
        int R = g * 256 + ns * 16 + r;
        int k = ks * 32 + kk;
        float v = (k < 256) ? Wih2[R * 256 + k] : Whh2[R * 256 + (k - 256)];
        unsigned short h = f2bf(v);
        size_t d = (size_t)(tile * 16 + ks) * 512 + off;
        w2h[d] = h; w2l[d] = f2bf(v - bf2f(h));
    }
    if (tid < 16) {
        int R = g * 256 + ns * 16 + tid;
        bias1[R] = bih1[R] + bhh1[R];
        bias2[R] = bih2[R] + bhh2[R];
    }
}

// xT[hi/lo]: [T][512][16] bf16 from x[512][T][16] fp32
__global__ void prep_x(const float* __restrict__ x,
                       unsigned short* __restrict__ xTh, unsigned short* __restrict__ xTl)
{
    int flat = blockIdx.x * 256 + threadIdx.x;       // T*512*16 = 365*8192
    int t = flat >> 13, rem = flat & 8191, b = rem >> 4, f = rem & 15;
    float v = x[((size_t)b * T_STEPS + t) * 16 + f];
    unsigned short h = f2bf(v);
    xTh[flat] = h; xTl[flat] = f2bf(v - bf2f(h));
}

// ---------------- main ----------------
__global__ __launch_bounds__(512) void lstm_main(
    const unsigned short* __restrict__ xTh, const unsigned short* __restrict__ xTl,
    const unsigned short* __restrict__ w1h, const unsigned short* __restrict__ w1l,
    const unsigned short* __restrict__ w2h, const unsigned short* __restrict__ w2l,
    const float* __restrict__ bias1, const float* __restrict__ bias2,
    unsigned short* hb1h, unsigned short* hb1l,
    unsigned short* hb2h, unsigned short* hb2l,
    unsigned int* flags,
    const float* __restrict__ Wlin, const float* __restrict__ blin,
    float* __restrict__ out)
{
    __shared__ __align__(16) unsigned short A2h[32][520];  // [h1 | h2] bf16-hi
    __shared__ __align__(16) unsigned short A2l[32][520];
    __shared__ __align__(16) unsigned short xh[32][32];
    __shared__ __align__(16) unsigned short xl[32][32];
    __shared__ __align__(16) float zb[2][32][68];          // [kh][row][col*4+g]
    __shared__ __align__(16) float hp[32][17];

    const int tid  = threadIdx.x;
    const int wv   = tid >> 6;            // 8 waves
    const int lane = tid & 63;
    const int quad = lane >> 4;
    const int r16  = lane & 15;
    const int g    = wv & 3;              // gate
    const int kh   = wv >> 2;             // K-half
    const int bg   = blockIdx.x & 15;     // batch group (XCD = bg%8)
    const int ns   = blockIdx.x >> 4;     // col slice
    const int tile = g * 16 + ns;
    const int loff = r16 * 32 + quad * 8; // lane offset within 1KB weight block

    const int urow = tid >> 4;            // updater: batch row 0..31
    const int ucol = tid & 15;            // local col 0..15
    const int colg = ns * 16 + ucol;      // global hidden col

    unsigned int* cnt = flags + (size_t)bg * 64;

    // biases for this thread's (col, 4 gates)
    float bi1[4], bi2[4];
#pragma unroll
    for (int gg = 0; gg < 4; gg++) {
        bi1[gg] = bias1[gg * 256 + colg];
        bi2[gg] = bias2[gg * 256 + colg];
    }

    // zero LDS
    for (int i = tid; i < 32 * 520; i += 512) { (&A2h[0][0])[i] = 0; (&A2l[0][0])[i] = 0; }
    for (int i = tid; i < 32 * 32;  i += 512) { (&xh[0][0])[i] = 0;  (&xl[0][0])[i] = 0; }

    float c1 = 0.f, c2 = 0.f;
    const unsigned short* w1h_t = w1h + (size_t)tile * 9 * 512;
    const unsigned short* w1l_t = w1l + (size_t)tile * 9 * 512;
    const unsigned short* w2h_t = w2h + (size_t)tile * 16 * 512;
    const unsigned short* w2l_t = w2l + (size_t)tile * 16 * 512;

    __syncthreads();

    for (int t = 0; t < T_STEPS; t++) {
        const int p = t & 1;

        // ---- stage x_t (1 elem/thread, coalesced) ----
        {
            size_t o = ((size_t)t * 512 + bg * 32 + urow) * 16 + ucol;
            xh[urow][ucol] = xTh[o];
            xl[urow][ucol] = xTl[o];
        }
        __syncthreads();  // xls ready; A2lds holds [h1_{t-1} | h2_{t-2}]

        // ================= P1: layer-1 GEMM (K=288) =================
        float4_ acc0 = {0.f, 0.f, 0.f, 0.f}, acc1 = {0.f, 0.f, 0.f, 0.f};

#define GEMM_BODY(WH, WL, KS, AH, AL)                                          \
        {                                                                      \
            const int ko = (KS & 7) * 32 + quad * 8; /* only used for A2 */    \
            (void)ko;                                                          \
            short8 b_hi = *(const short8*)(WH + (size_t)(KS) * 512 + loff);    \
            short8 b_lo = *(const short8*)(WL + (size_t)(KS) * 512 + loff);    \
            short8 ah0 = AH(r16), al0 = AL(r16);                               \
            short8 ah1 = AH(r16 + 16), al1 = AL(r16 + 16);                     \
            acc0 = MFMA16(ah0, b_hi, acc0);                                    \
            acc1 = MFMA16(ah1, b_hi, acc1);                                    \
            acc0 = MFMA16(al0, b_hi, acc0);                                    \
            acc1 = MFMA16(al1, b_hi, acc1);                                    \
            acc0 = MFMA16(ah0, b_lo, acc0);                                    \
            acc1 = MFMA16(ah1, b_lo, acc1);                                    \
        }

        if (kh == 0) {
#pragma unroll
            for (int ks = 0; ks < 5; ks++) {
#define AH_A2(r) (*(const short8*)&A2h[r][ks * 32 + quad * 8])
#define AL_A2(r) (*(const short8*)&A2l[r][ks * 32 + quad * 8])
                GEMM_BODY(w1h_t, w1l_t, ks, AH_A2, AL_A2)
#undef AH_A2
#undef AL_A2
            }
        } else {
#pragma unroll
            for (int ks = 5; ks < 8; ks++) {
#define AH_A2(r) (*(const short8*)&A2h[r][ks * 32 + quad * 8])
#define AL_A2(r) (*(const short8*)&A2l[r][ks * 32 + quad * 8])
                GEMM_BODY(w1h_t, w1l_t, ks, AH_A2, AL_A2)
#undef AH_A2
#undef AL_A2
            }
            {   // x block (ks = 8)
#define AH_X(r) (*(const short8*)&xh[r][quad * 8])
#define AL_X(r) (*(const short8*)&xl[r][quad * 8])
                GEMM_BODY(w1h_t, w1l_t, 8, AH_X, AL_X)
#undef AH_X
#undef AL_X
            }
        }

#pragma unroll
        for (int rr = 0; rr < 4; rr++) {
            zb[kh][quad * 4 + rr][r16 * 4 + g]      = acc0[rr];
            zb[kh][quad * 4 + rr + 16][r16 * 4 + g] = acc1[rr];
        }
        __syncthreads();

        // ---- P1 update: h1, publish ----
        {
            float4_ z0 = *(const float4_*)&zb[0][urow][ucol * 4];
            float4_ z1 = *(const float4_*)&zb[1][urow][ucol * 4];
            float zi = z0[0] + z1[0] + bi1[0];
            float zf = z0[1] + z1[1] + bi1[1];
            float zg = z0[2] + z1[2] + bi1[2];
            float zo = z0[3] + z1[3] + bi1[3];
            c1 = sigm(zf) * c1 + sigm(zi) * tanh_(zg);
            float h = sigm(zo) * tanh_(c1);
            size_t o = (((size_t)p * 16 + bg) * 32 + urow) * 256 + colg;
            unsigned short hh = f2bf(h);
            hb1h[o] = hh; hb1l[o] = f2bf(h - bf2f(hh));
        }

        // ---- barrier B1: all 16 slice-WGs published h1_t ----
        __syncthreads();
        if (tid == 0) {
            __threadfence();
            __hip_atomic_fetch_add(cnt, 1u, __ATOMIC_ACQ_REL, __HIP_MEMORY_SCOPE_AGENT);
            unsigned int tgt = 16u * (2u * t + 1u);
            while (__hip_atomic_load(cnt, __ATOMIC_ACQUIRE, __HIP_MEMORY_SCOPE_AGENT) < tgt) {}
        }
        __syncthreads();

        // ---- stage A2 = [h1_t | h2_{t-1}] into LDS ----
        {
            int seg = ucol;  // 16 segs x 16 ushorts (32B) per row per plane
            size_t o1 = (((size_t)p * 16 + bg) * 32 + urow) * 256 + seg * 16;
            size_t o2 = (((size_t)(1 - p) * 16 + bg) * 32 + urow) * 256 + seg * 16;
#pragma unroll
            for (int j = 0; j < 2; j++) {
                *(ushort8*)&A2h[urow][seg * 16 + j * 8]       = *(const ushort8*)&hb1h[o1 + j * 8];
                *(ushort8*)&A2l[urow][seg * 16 + j * 8]       = *(const ushort8*)&hb1l[o1 + j * 8];
                *(ushort8*)&A2h[urow][256 + seg * 16 + j * 8] = *(const ushort8*)&hb2h[o2 + j * 8];
                *(ushort8*)&A2l[urow][256 + seg * 16 + j * 8] = *(const ushort8*)&hb2l[o2 + j * 8];
            }
        }
        __syncthreads();

        // ================= P2: layer-2 GEMM (K=512) =================
        acc0 = (float4_){0.f, 0.f, 0.f, 0.f};
        acc1 = (float4_){0.f, 0.f, 0.f, 0.f};
        {
            const int kb = kh * 8;
#pragma unroll
            for (int ks2 = 0; ks2 < 8; ks2++) {
                const int ks = kb + ks2;
#define AH_A2(r) (*(const short8*)&A2h[r][ks * 32 + quad * 8])
#define AL_A2(r) (*(const short8*)&A2l[r][ks * 32 + quad * 8])
                GEMM_BODY(w2h_t, w2l_t, ks, AH_A2, AL_A2)
#undef AH_A2
#undef AL_A2
            }
        }
#pragma unroll
        for (int rr = 0; rr < 4; rr++) {
            zb[kh][quad * 4 + rr][r16 * 4 + g]      = acc0[rr];
            zb[kh][quad * 4 + rr + 16][r16 * 4 + g] = acc1[rr];
        }
        __syncthreads();

        // ---- P2 update: h2, publish ----
        {
            float4_ z0 = *(const float4_*)&zb[0][urow][ucol * 4];
            float4_ z1 = *(const float4_*)&zb[1][urow][ucol * 4];
            float zi = z0[0] + z1[0] + bi2[0];
            float zf = z0[1] + z1[1] + bi2[1];
            float zg = z0[2] + z1[2] + bi2[2];
            float zo = z0[3] + z1[3] + bi2[3];
            c2 = sigm(zf) * c2 + sigm(zi) * tanh_(zg);
            float h = sigm(zo) * tanh_(c2);
            size_t o = (((size_t)p * 16 + bg) * 32 + urow) * 256 + colg;
            unsigned short hh = f2bf(h);
            hb2h[o] = hh; hb2l[o] = f2bf(h - bf2f(hh));
        }

        // ---- barrier B2 ----
        __syncthreads();
        if (tid == 0) {
            __threadfence();
            __hip_atomic_fetch_add(cnt, 1u, __ATOMIC_ACQ_REL, __HIP_MEMORY_SCOPE_AGENT);
            unsigned int tgt = 16u * (2u * t + 2u);
            while (__hip_atomic_load(cnt, __ATOMIC_ACQUIRE, __HIP_MEMORY_SCOPE_AGENT) < tgt) {}
        }
        __syncthreads();
    }

    // ---- head (ns==0 WGs): out[b] = h2_T[b] . Wlin + blin ----
    if (ns != 0) return;
    {
        int row = tid >> 4, seg = tid & 15;  // final parity = (364 & 1) = 0
        size_t o = (((size_t)bg) * 32 + row) * 256 + seg * 16;
        float s = 0.f;
#pragma unroll
        for (int j = 0; j < 16; j++)
            s += (bf2f(hb2h[o + j]) + bf2f(hb2l[o + j])) * Wlin[seg * 16 + j];
        hp[row][seg] = s;
    }
    __syncthreads();
    if (tid < 32) {
        float s = 0.f;
#pragma unroll
        for (int j = 0; j < 16; j++) s += hp[tid][j];
        out[bg * 32 + tid] = s + blin[0];
    }
}

extern "C" void kernel_launch(void* const* d_in, const int* in_sizes, int n_in,
                              void* d_out, int out_size, void* d_ws, size_t ws_size,
                              hipStream_t stream) {
    const float* x    = (const float*)d_in[0];
    const float* Wih1 = (const float*)d_in[1];
    const float* Whh1 = (const float*)d_in[2];
    const float* bih1 = (const float*)d_in[3];
    const float* bhh1 = (const float*)d_in[4];
    const float* Wih2 = (const float*)d_in[5];
    const float* Whh2 = (const float*)d_in[6];
    const float* bih2 = (const float*)d_in[7];
    const float* bhh2 = (const float*)d_in[8];
    const float* Wlin = (const float*)d_in[9];
    const float* blin = (const float*)d_in[10];
    float* out = (float*)d_out;

    char* pp = (char*)d_ws;
    unsigned short* w1h = (unsigned short*)pp; pp += (size_t)64 * 9 * 512 * 2;    // 589,824
    unsigned short* w1l = (unsigned short*)pp; pp += (size_t)64 * 9 * 512 * 2;
    unsigned short* w2h = (unsigned short*)pp; pp += (size_t)64 * 16 * 512 * 2;   // 1,048,576
    unsigned short* w2l = (unsigned short*)pp; pp += (size_t)64 * 16 * 512 * 2;
    float* bias1 = (float*)pp; pp += 1024 * 4;
    float* bias2 = (float*)pp; pp += 1024 * 4;
    unsigned short* xTh = (unsigned short*)pp; pp += (size_t)T_STEPS * 512 * 16 * 2;  // 5,980,160
    unsigned short* xTl = (unsigned short*)pp; pp += (size_t)T_STEPS * 512 * 16 * 2;
    char* zero_base = pp;
    unsigned short* hb1h = (unsigned short*)pp; pp += (size_t)2 * 16 * 32 * 256 * 2;  // 524,288
    unsigned short* hb1l = (unsigned short*)pp; pp += (size_t)2 * 16 * 32 * 256 * 2;
    unsigned short* hb2h = (unsigned short*)pp; pp += (size_t)2 * 16 * 32 * 256 * 2;
    unsigned short* hb2l = (unsigned short*)pp; pp += (size_t)2 * 16 * 32 * 256 * 2;
    unsigned int* flags  = (unsigned int*)pp;  pp += 16 * 64 * 4;                     // 4,096
    size_t zero_bytes = (size_t)(pp - zero_base);

    hipMemsetAsync(zero_base, 0, zero_bytes, stream);
    prep_w<<<64, 256, 0, stream>>>(Wih1, Whh1, bih1, bhh1, Wih2, Whh2, bih2, bhh2,
                                   w1h, w1l, w2h, w2l, bias1, bias2);
    prep_x<<<(T_STEPS * 512 * 16) / 256, 256, 0, stream>>>(x, xTh, xTl);
    lstm_main<<<256, 512, 0, stream>>>(xTh, xTl, w1h, w1l, w2h, w2l, bias1, bias2,
                                       hb1h, hb1l, hb2h, hb2l, flags, Wlin, blin, out);
}

// Round 3
// 3886.149 us; speedup vs baseline: 8.1142x; 2.9173x over previous
//
#include <hip/hip_runtime.h>

// LSTM_38869454028951: B=512, T=365, F=16, H=256, 2 layers + linear head.
// Round 3: fence-free handoff. 16 bg x 16 ns = 256 WGs x 512 thr, 1 WG/CU.
// Cross-WG h via relaxed agent-scope atomics (cache-bypassing, no wbl2/inv);
// per-WG progress slots replace the (racy) sum-counter barrier. One wait/step.

#define T_STEPS 365

typedef __attribute__((ext_vector_type(8))) short short8;
typedef __attribute__((ext_vector_type(8))) unsigned short ushort8;
typedef __attribute__((ext_vector_type(4))) float float4_;
typedef unsigned long long u64;

#define MFMA16(a, b, c) __builtin_amdgcn_mfma_f32_16x16x32_bf16((a), (b), (c), 0, 0, 0)

__device__ __forceinline__ unsigned short f2bf(float v) {
    union { float f; unsigned int u; } a; a.f = v;
    unsigned int r = a.u + 0x7fffu + ((a.u >> 16) & 1u);  // RNE
    return (unsigned short)(r >> 16);
}
__device__ __forceinline__ float bf2f(unsigned short h) {
    union { unsigned int u; float f; } a; a.u = ((unsigned int)h) << 16; return a.f;
}
__device__ __forceinline__ float sigm(float x)  { return 1.f / (1.f + __expf(-x)); }
__device__ __forceinline__ float tanh_(float x) { return 2.f / (1.f + __expf(-2.f * x)) - 1.f; }

// ---------------- prep: blocked hi/lo weights + biases (unchanged layout) ----------------
__global__ void prep_w(
    const float* __restrict__ Wih1, const float* __restrict__ Whh1,
    const float* __restrict__ bih1, const float* __restrict__ bhh1,
    const float* __restrict__ Wih2, const float* __restrict__ Whh2,
    const float* __restrict__ bih2, const float* __restrict__ bhh2,
    unsigned short* __restrict__ w1h, unsigned short* __restrict__ w1l,
    unsigned short* __restrict__ w2h, unsigned short* __restrict__ w2l,
    float* __restrict__ bias1, float* __restrict__ bias2)
{
    const int tile = blockIdx.x;          // 64
    const int g = tile >> 4, ns = tile & 15;
    const int tid = threadIdx.x;          // 256

    for (int idx = tid; idx < 9 * 512; idx += 256) {
        int ks = idx >> 9, off = idx & 511, r = off >> 5, kk = off & 31;
        int R = g * 256 + ns * 16 + r;
        float v;
        if (ks < 8)      v = Whh1[R * 256 + ks * 32 + kk];
        else if (kk < 16) v = Wih1[R * 16 + kk];
        else             v = 0.f;
        unsigned short h = f2bf(v);
        size_t d = (size_t)(tile * 9 + ks) * 512 + off;
        w1h[d] = h; w1l[d] = f2bf(v - bf2f(h));
    }
    for (int idx = tid; idx < 16 * 512; idx += 256) {
        int ks = idx >> 9, off = idx & 511, r = off >> 5, kk = off & 31;
        int R = g * 256 + ns * 16 + r;
        int k = ks * 32 + kk;
        float v = (k < 256) ? Wih2[R * 256 + k] : Whh2[R * 256 + (k - 256)];
        unsigned short h = f2bf(v);
        size_t d = (size_t)(tile * 16 + ks) * 512 + off;
        w2h[d] = h; w2l[d] = f2bf(v - bf2f(h));
    }
    if (tid < 16) {
        int R = g * 256 + ns * 16 + tid;
        bias1[R] = bih1[R] + bhh1[R];
        bias2[R] = bih2[R] + bhh2[R];
    }
}

// stage 16 consecutive f32 (agent-scope atomic u64 loads) -> bf16 hi/lo LDS
__device__ __forceinline__ void stage16(const float* src, unsigned short* dh, unsigned short* dl) {
    float v[16];
#pragma unroll
    for (int j = 0; j < 8; j++) {
        union { u64 u; float f[2]; } a;
        a.u = __hip_atomic_load((const u64*)src + j, __ATOMIC_RELAXED, __HIP_MEMORY_SCOPE_AGENT);
        v[2 * j] = a.f[0]; v[2 * j + 1] = a.f[1];
    }
    ushort8 H0, H1, L0, L1;
#pragma unroll
    for (int k = 0; k < 8; k++) {
        unsigned short h0 = f2bf(v[k]);     H0[k] = h0; L0[k] = f2bf(v[k] - bf2f(h0));
        unsigned short h1 = f2bf(v[k + 8]); H1[k] = h1; L1[k] = f2bf(v[k + 8] - bf2f(h1));
    }
    *(ushort8*)(dh) = H0; *(ushort8*)(dh + 8) = H1;
    *(ushort8*)(dl) = L0; *(ushort8*)(dl + 8) = L1;
}

// ---------------- main ----------------
__global__ __launch_bounds__(512) void lstm_main(
    const float* __restrict__ x,
    const unsigned short* __restrict__ w1h, const unsigned short* __restrict__ w1l,
    const unsigned short* __restrict__ w2h, const unsigned short* __restrict__ w2l,
    const float* __restrict__ bias1, const float* __restrict__ bias2,
    float* hb1, float* hb2, unsigned int* prog,
    const float* __restrict__ Wlin, const float* __restrict__ blin,
    float* __restrict__ out)
{
    __shared__ __align__(16) unsigned short A2h[32][520];  // [h1 | h2] bf16-hi
    __shared__ __align__(16) unsigned short A2l[32][520];
    __shared__ __align__(16) unsigned short xh[32][32];
    __shared__ __align__(16) unsigned short xl[32][32];
    __shared__ __align__(16) float zb[2][32][4][17];       // [kh][row][gate][col+pad]
    __shared__ __align__(16) float hp[32][17];

    const int tid  = threadIdx.x;
    const int lane = tid & 63;
    const int wv   = tid >> 6;            // 8 waves
    const int quad = lane >> 4;
    const int r16  = lane & 15;
    const int g    = wv & 3;              // gate
    const int kh   = wv >> 2;             // K-half
    const int bg   = blockIdx.x & 15;     // batch group
    const int ns   = blockIdx.x >> 4;     // col slice
    const int tile = g * 16 + ns;
    const int loff = r16 * 32 + quad * 8;

    const int urow = tid >> 4;            // updater: batch row 0..31
    const int ucol = tid & 15;            // local col 0..15
    const int colg = ns * 16 + ucol;      // global hidden col

    unsigned int* myprog = prog + bg * 16;

    float bi1[4], bi2[4];
#pragma unroll
    for (int gg = 0; gg < 4; gg++) {
        bi1[gg] = bias1[gg * 256 + colg];
        bi2[gg] = bias2[gg * 256 + colg];
    }

    for (int i = tid; i < 32 * 520; i += 512) { (&A2h[0][0])[i] = 0; (&A2l[0][0])[i] = 0; }
    for (int i = tid; i < 32 * 32;  i += 512) { (&xh[0][0])[i] = 0;  (&xl[0][0])[i] = 0; }

    float c1 = 0.f, c2 = 0.f;
    const unsigned short* w1h_t = w1h + (size_t)tile * 9 * 512;
    const unsigned short* w1l_t = w1l + (size_t)tile * 9 * 512;
    const unsigned short* w2h_t = w2h + (size_t)tile * 16 * 512;
    const unsigned short* w2l_t = w2l + (size_t)tile * 16 * 512;

    __syncthreads();

    for (int t = 0; t < T_STEPS; t++) {
        const int p = t & 1;

        // ---- stage x_t from global fp32 (L2-hot, 2KB/WG) ----
        {
            float v = x[((size_t)(bg * 32 + urow) * T_STEPS + t) * 16 + ucol];
            unsigned short h = f2bf(v);
            xh[urow][ucol] = h;
            xl[urow][ucol] = f2bf(v - bf2f(h));
        }
        __syncthreads();   // (1) x ready; A2 = [h1_{t-1} | h2_{t-2}]

        // ================= P1: layer-1 GEMM (K=288) =================
        float4_ acc0 = {0.f, 0.f, 0.f, 0.f}, acc1 = {0.f, 0.f, 0.f, 0.f};

#define GEMM_BODY(WH, WL, KS, AH, AL)                                          \
        {                                                                      \
            short8 b_hi = *(const short8*)(WH + (size_t)(KS) * 512 + loff);    \
            short8 b_lo = *(const short8*)(WL + (size_t)(KS) * 512 + loff);    \
            short8 ah0 = AH(r16), al0 = AL(r16);                               \
            short8 ah1 = AH(r16 + 16), al1 = AL(r16 + 16);                     \
            acc0 = MFMA16(ah0, b_hi, acc0);                                    \
            acc1 = MFMA16(ah1, b_hi, acc1);                                    \
            acc0 = MFMA16(al0, b_hi, acc0);                                    \
            acc1 = MFMA16(al1, b_hi, acc1);                                    \
            acc0 = MFMA16(ah0, b_lo, acc0);                                    \
            acc1 = MFMA16(ah1, b_lo, acc1);                                    \
        }

        if (kh == 0) {
#pragma unroll
            for (int ks = 0; ks < 5; ks++) {
#define AH_A2(r) (*(const short8*)&A2h[r][ks * 32 + quad * 8])
#define AL_A2(r) (*(const short8*)&A2l[r][ks * 32 + quad * 8])
                GEMM_BODY(w1h_t, w1l_t, ks, AH_A2, AL_A2)
#undef AH_A2
#undef AL_A2
            }
        } else {
#pragma unroll
            for (int ks = 5; ks < 8; ks++) {
#define AH_A2(r) (*(const short8*)&A2h[r][ks * 32 + quad * 8])
#define AL_A2(r) (*(const short8*)&A2l[r][ks * 32 + quad * 8])
                GEMM_BODY(w1h_t, w1l_t, ks, AH_A2, AL_A2)
#undef AH_A2
#undef AL_A2
            }
            {
#define AH_X(r) (*(const short8*)&xh[r][quad * 8])
#define AL_X(r) (*(const short8*)&xl[r][quad * 8])
                GEMM_BODY(w1h_t, w1l_t, 8, AH_X, AL_X)
#undef AH_X
#undef AL_X
            }
        }

#pragma unroll
        for (int rr = 0; rr < 4; rr++) {
            zb[kh][quad * 4 + rr][g][r16]      = acc0[rr];
            zb[kh][quad * 4 + rr + 16][g][r16] = acc1[rr];
        }
        __syncthreads();   // (2) zb ready; A2 h1-reads done

        // ---- P1 update: h1_t, publish (relaxed agent f32 stores) ----
        {
            float zi = zb[0][urow][0][ucol] + zb[1][urow][0][ucol] + bi1[0];
            float zf = zb[0][urow][1][ucol] + zb[1][urow][1][ucol] + bi1[1];
            float zg = zb[0][urow][2][ucol] + zb[1][urow][2][ucol] + bi1[2];
            float zo = zb[0][urow][3][ucol] + zb[1][urow][3][ucol] + bi1[3];
            c1 = sigm(zf) * c1 + sigm(zi) * tanh_(zg);
            float h = sigm(zo) * tanh_(c1);
            size_t o = (((size_t)p * 16 + bg) * 32 + urow) * 256 + colg;
            __hip_atomic_store(&hb1[o], h, __ATOMIC_RELAXED, __HIP_MEMORY_SCOPE_AGENT);
        }
        __syncthreads();   // (3) drains vmcnt: all publishes complete

        // ---- milestone 2t+1 + wait for peers' h1_t (covers h2_{t-1} too) ----
        if (tid == 0)
            __hip_atomic_store(&myprog[ns], (unsigned)(2 * t + 1),
                               __ATOMIC_RELAXED, __HIP_MEMORY_SCOPE_AGENT);
        asm volatile("" ::: "memory");
        if (tid < 16) {
            while (__hip_atomic_load(&myprog[tid], __ATOMIC_RELAXED,
                                     __HIP_MEMORY_SCOPE_AGENT) < (unsigned)(2 * t + 1)) {}
        }
        __syncthreads();   // (4) all peers published h1_t; safe to restage A2

        // ---- stage A2 = [h1_t | h2_{t-1}] (f32 -> hi/lo) ----
        {
            const float* s1 = hb1 + (((size_t)p * 16 + bg) * 32 + urow) * 256 + ucol * 16;
            const float* s2 = hb2 + (((size_t)(1 - p) * 16 + bg) * 32 + urow) * 256 + ucol * 16;
            stage16(s1, &A2h[urow][ucol * 16],       &A2l[urow][ucol * 16]);
            stage16(s2, &A2h[urow][256 + ucol * 16], &A2l[urow][256 + ucol * 16]);
        }
        __syncthreads();   // (5) A2 ready

        // ================= P2: layer-2 GEMM (K=512) =================
        acc0 = (float4_){0.f, 0.f, 0.f, 0.f};
        acc1 = (float4_){0.f, 0.f, 0.f, 0.f};
        {
            const int kb = kh * 8;
#pragma unroll
            for (int ks2 = 0; ks2 < 8; ks2++) {
                const int ks = kb + ks2;
#define AH_A2(r) (*(const short8*)&A2h[r][ks * 32 + quad * 8])
#define AL_A2(r) (*(const short8*)&A2l[r][ks * 32 + quad * 8])
                GEMM_BODY(w2h_t, w2l_t, ks, AH_A2, AL_A2)
#undef AH_A2
#undef AL_A2
            }
        }
#pragma unroll
        for (int rr = 0; rr < 4; rr++) {
            zb[kh][quad * 4 + rr][g][r16]      = acc0[rr];
            zb[kh][quad * 4 + rr + 16][g][r16] = acc1[rr];
        }
        __syncthreads();   // (6)

        // ---- P2 update: h2_t, publish ----
        {
            float zi = zb[0][urow][0][ucol] + zb[1][urow][0][ucol] + bi2[0];
            float zf = zb[0][urow][1][ucol] + zb[1][urow][1][ucol] + bi2[1];
            float zg = zb[0][urow][2][ucol] + zb[1][urow][2][ucol] + bi2[2];
            float zo = zb[0][urow][3][ucol] + zb[1][urow][3][ucol] + bi2[3];
            c2 = sigm(zf) * c2 + sigm(zi) * tanh_(zg);
            float h = sigm(zo) * tanh_(c2);
            size_t o = (((size_t)p * 16 + bg) * 32 + urow) * 256 + colg;
            __hip_atomic_store(&hb2[o], h, __ATOMIC_RELAXED, __HIP_MEMORY_SCOPE_AGENT);
        }
        __syncthreads();   // (7) drains publishes

        if (tid == 0)
            __hip_atomic_store(&myprog[ns], (unsigned)(2 * t + 2),
                               __ATOMIC_RELAXED, __HIP_MEMORY_SCOPE_AGENT);
        // no wait here: next step's wait (>= 2(t+1)+1) implies peers passed 2t+2
    }

    // ---- head (ns==0): out[b] = h2_T . Wlin + blin ; final parity p=0 ----
    if (tid < 16) {
        while (__hip_atomic_load(&myprog[tid], __ATOMIC_RELAXED,
                                 __HIP_MEMORY_SCOPE_AGENT) < (unsigned)(2 * T_STEPS)) {}
    }
    __syncthreads();
    if (ns != 0) return;
    {
        int row = tid >> 4, seg = tid & 15;
        const float* src = hb2 + ((size_t)bg * 32 + row) * 256 + seg * 16;
        float s = 0.f;
#pragma unroll
        for (int j = 0; j < 16; j++)
            s += __hip_atomic_load(&src[j], __ATOMIC_RELAXED, __HIP_MEMORY_SCOPE_AGENT)
                 * Wlin[seg * 16 + j];
        hp[row][seg] = s;
    }
    __syncthreads();
    if (tid < 32) {
        float s = 0.f;
#pragma unroll
        for (int j = 0; j < 16; j++) s += hp[tid][j];
        out[bg * 32 + tid] = s + blin[0];
    }
}

extern "C" void kernel_launch(void* const* d_in, const int* in_sizes, int n_in,
                              void* d_out, int out_size, void* d_ws, size_t ws_size,
                              hipStream_t stream) {
    const float* x    = (const float*)d_in[0];
    const float* Wih1 = (const float*)d_in[1];
    const float* Whh1 = (const float*)d_in[2];
    const float* bih1 = (const float*)d_in[3];
    const float* bhh1 = (const float*)d_in[4];
    const float* Wih2 = (const float*)d_in[5];
    const float* Whh2 = (const float*)d_in[6];
    const float* bih2 = (const float*)d_in[7];
    const float* bhh2 = (const float*)d_in[8];
    const float* Wlin = (const float*)d_in[9];
    const float* blin = (const float*)d_in[10];
    float* out = (float*)d_out;

    char* pp = (char*)d_ws;
    unsigned short* w1h = (unsigned short*)pp; pp += (size_t)64 * 9 * 512 * 2;
    unsigned short* w1l = (unsigned short*)pp; pp += (size_t)64 * 9 * 512 * 2;
    unsigned short* w2h = (unsigned short*)pp; pp += (size_t)64 * 16 * 512 * 2;
    unsigned short* w2l = (unsigned short*)pp; pp += (size_t)64 * 16 * 512 * 2;
    float* bias1 = (float*)pp; pp += 1024 * 4;
    float* bias2 = (float*)pp; pp += 1024 * 4;
    char* zero_base = pp;
    float* hb1 = (float*)pp; pp += (size_t)2 * 16 * 32 * 256 * 4;   // 1 MB
    float* hb2 = (float*)pp; pp += (size_t)2 * 16 * 32 * 256 * 4;   // 1 MB
    unsigned int* prog = (unsigned int*)pp; pp += 16 * 16 * 4;
    size_t zero_bytes = (size_t)(pp - zero_base);

    hipMemsetAsync(zero_base, 0, zero_bytes, stream);
    prep_w<<<64, 256, 0, stream>>>(Wih1, Whh1, bih1, bhh1, Wih2, Whh2, bih2, bhh2,
                                   w1h, w1l, w2h, w2l, bias1, bias2);
    lstm_main<<<256, 512, 0, stream>>>(x, w1h, w1l, w2h, w2l, bias1, bias2,
                                       hb1, hb2, prog, Wlin, blin, out);
}

// Round 4
// 2734.136 us; speedup vs baseline: 11.5330x; 1.4213x over previous
//
#include <hip/hip_runtime.h>

// LSTM_38869454028951: B=512, T=365, F=16, H=256, 2 layers + linear head.
// Round 4: retimed pipeline. Body i computes h1_i AND h2_{i-1} in ONE merged
// GEMM phase over A=[h1_{i-1} | x_i | h2_{i-2}] (K=544); one sync RTT per body
// (366 bodies), 3 barriers/body. Weights live in REGISTERS (24-26KB/wave,
// loaded once). h published as packed (bf16hi|bf16lo) u32.

#define T_STEPS 365
#define ASTR 552   // A2 row stride (ushorts); 16B-aligned rows

typedef __attribute__((ext_vector_type(8))) short short8;
typedef __attribute__((ext_vector_type(8))) unsigned short ushort8;
typedef __attribute__((ext_vector_type(4))) float float4_;
typedef unsigned long long u64;
typedef unsigned int u32;

#define MFMA16(a, b, c) __builtin_amdgcn_mfma_f32_16x16x32_bf16((a), (b), (c), 0, 0, 0)

__device__ __forceinline__ unsigned short f2bf(float v) {
    union { float f; u32 u; } a; a.f = v;
    u32 r = a.u + 0x7fffu + ((a.u >> 16) & 1u);  // RNE
    return (unsigned short)(r >> 16);
}
__device__ __forceinline__ float bf2f(unsigned short h) {
    union { u32 u; float f; } a; a.u = ((u32)h) << 16; return a.f;
}
__device__ __forceinline__ u32 packhl(float v) {
    unsigned short hi = f2bf(v);
    unsigned short lo = f2bf(v - bf2f(hi));
    return ((u32)hi << 16) | (u32)lo;
}
__device__ __forceinline__ float sigm(float x)  { return 1.f / (1.f + __expf(-x)); }
__device__ __forceinline__ float tanh_(float x) { return 2.f / (1.f + __expf(-2.f * x)) - 1.f; }

// ---------------- prep: blocked hi/lo weights + biases ----------------
// w1blk: [64 tiles][9 ks][16 rows][32 k]; ks<8: Whh1; ks==8: Wih1 (K pad 16->32)
// w2blk: [64][16][16][32]; ks<8: Wih2 (h1 input), ks>=8: Whh2 (h2 input)
__global__ void prep_w(
    const float* __restrict__ Wih1, const float* __restrict__ Whh1,
    const float* __restrict__ bih1, const float* __restrict__ bhh1,
    const float* __restrict__ Wih2, const float* __restrict__ Whh2,
    const float* __restrict__ bih2, const float* __restrict__ bhh2,
    unsigned short* __restrict__ w1h, unsigned short* __restrict__ w1l,
    unsigned short* __restrict__ w2h, unsigned short* __restrict__ w2l,
    float* __restrict__ bias1, float* __restrict__ bias2)
{
    const int tile = blockIdx.x;          // 64
    const int g = tile >> 4, ns = tile & 15;
    const int tid = threadIdx.x;          // 256

    for (int idx = tid; idx < 9 * 512; idx += 256) {
        int ks = idx >> 9, off = idx & 511, r = off >> 5, kk = off & 31;
        int R = g * 256 + ns * 16 + r;
        float v;
        if (ks < 8)       v = Whh1[R * 256 + ks * 32 + kk];
        else if (kk < 16) v = Wih1[R * 16 + kk];
        else              v = 0.f;
        unsigned short h = f2bf(v);
        size_t d = (size_t)(tile * 9 + ks) * 512 + off;
        w1h[d] = h; w1l[d] = f2bf(v - bf2f(h));
    }
    for (int idx = tid; idx < 16 * 512; idx += 256) {
        int ks = idx >> 9, off = idx & 511, r = off >> 5, kk = off & 31;
        int R = g * 256 + ns * 16 + r;
        int k = ks * 32 + kk;
        float v = (k < 256) ? Wih2[R * 256 + k] : Whh2[R * 256 + (k - 256)];
        unsigned short h = f2bf(v);
        size_t d = (size_t)(tile * 16 + ks) * 512 + off;
        w2h[d] = h; w2l[d] = f2bf(v - bf2f(h));
    }
    if (tid < 16) {
        int R = g * 256 + ns * 16 + tid;
        bias1[R] = bih1[R] + bhh1[R];
        bias2[R] = bih2[R] + bhh2[R];
    }
}

// stage 16 packed u32 (8 agent u64 loads) -> bf16 hi/lo LDS (shift unpack)
__device__ __forceinline__ void stage16p(const u32* src, unsigned short* dh, unsigned short* dl) {
    ushort8 H0, H1, L0, L1;
#pragma unroll
    for (int j = 0; j < 4; j++) {
        u64 v = __hip_atomic_load((const u64*)src + j, __ATOMIC_RELAXED, __HIP_MEMORY_SCOPE_AGENT);
        u32 a = (u32)v, b = (u32)(v >> 32);
        H0[2 * j] = (unsigned short)(a >> 16);   L0[2 * j] = (unsigned short)a;
        H0[2 * j + 1] = (unsigned short)(b >> 16); L0[2 * j + 1] = (unsigned short)b;
    }
#pragma unroll
    for (int j = 0; j < 4; j++) {
        u64 v = __hip_atomic_load((const u64*)src + 4 + j, __ATOMIC_RELAXED, __HIP_MEMORY_SCOPE_AGENT);
        u32 a = (u32)v, b = (u32)(v >> 32);
        H1[2 * j] = (unsigned short)(a >> 16);   L1[2 * j] = (unsigned short)a;
        H1[2 * j + 1] = (unsigned short)(b >> 16); L1[2 * j + 1] = (unsigned short)b;
    }
    *(ushort8*)(dh) = H0; *(ushort8*)(dh + 8) = H1;
    *(ushort8*)(dl) = L0; *(ushort8*)(dl + 8) = L1;
}

// ---------------- main ----------------
__global__ __launch_bounds__(512, 2) void lstm_main(
    const float* __restrict__ x,
    const unsigned short* __restrict__ w1h, const unsigned short* __restrict__ w1l,
    const unsigned short* __restrict__ w2h, const unsigned short* __restrict__ w2l,
    const float* __restrict__ bias1, const float* __restrict__ bias2,
    u32* hb1, u32* hb2, u32* prog,
    const float* __restrict__ Wlin, const float* __restrict__ blin,
    float* __restrict__ out)
{
    // A = [h1 (cols 0..255) | x (256..287, 272+ zero-pad) | h2 (288..543)]
    __shared__ __align__(16) unsigned short A2h[32][ASTR];
    __shared__ __align__(16) unsigned short A2l[32][ASTR];
    __shared__ __align__(16) float zb1[2][32][4][17];
    __shared__ __align__(16) float zb2[2][32][4][17];
    __shared__ __align__(16) float hp[32][17];

    const int tid  = threadIdx.x;
    const int lane = tid & 63;
    const int wv   = tid >> 6;            // 8 waves
    const int quad = lane >> 4;
    const int r16  = lane & 15;
    const int g    = wv & 3;              // gate
    const int kh   = wv >> 2;             // K-half
    const int bg   = blockIdx.x & 15;     // batch group (XCD-local group)
    const int ns   = blockIdx.x >> 4;     // col slice
    const int tile = g * 16 + ns;
    const int loff = r16 * 32 + quad * 8;

    const int urow = tid >> 4;            // updater: batch row 0..31
    const int ucol = tid & 15;            // local col 0..15
    const int colg = ns * 16 + ucol;      // global hidden col

    u32* myprog = prog + bg * 16;

    float bi1[4], bi2[4];
#pragma unroll
    for (int gg = 0; gg < 4; gg++) {
        bi1[gg] = bias1[gg * 256 + colg];
        bi2[gg] = bias2[gg * 256 + colg];
    }

    // ---- preload weights into registers (once) ----
    const unsigned short* w1h_t = w1h + (size_t)tile * 9 * 512;
    const unsigned short* w1l_t = w1l + (size_t)tile * 9 * 512;
    const unsigned short* w2h_t = w2h + (size_t)tile * 16 * 512;
    const unsigned short* w2l_t = w2l + (size_t)tile * 16 * 512;

    short8 W1H[5], W1L[5], W2H[8], W2L[8];
    if (kh == 0) {
#pragma unroll
        for (int b = 0; b < 5; b++) {
            W1H[b] = *(const short8*)(w1h_t + (size_t)b * 512 + loff);
            W1L[b] = *(const short8*)(w1l_t + (size_t)b * 512 + loff);
        }
#pragma unroll
        for (int j = 0; j < 8; j++) {
            W2H[j] = *(const short8*)(w2h_t + (size_t)j * 512 + loff);
            W2L[j] = *(const short8*)(w2l_t + (size_t)j * 512 + loff);
        }
    } else {
#pragma unroll
        for (int b = 0; b < 4; b++) {
            W1H[b] = *(const short8*)(w1h_t + (size_t)(5 + b) * 512 + loff);
            W1L[b] = *(const short8*)(w1l_t + (size_t)(5 + b) * 512 + loff);
        }
        W1H[4] = short8{0,0,0,0,0,0,0,0}; W1L[4] = short8{0,0,0,0,0,0,0,0};
#pragma unroll
        for (int j = 0; j < 8; j++) {
            W2H[j] = *(const short8*)(w2h_t + (size_t)(8 + j) * 512 + loff);
            W2L[j] = *(const short8*)(w2l_t + (size_t)(8 + j) * 512 + loff);
        }
    }

    // ---- zero A LDS; stage x_0 ----
    for (int i = tid; i < 32 * ASTR; i += 512) { (&A2h[0][0])[i] = 0; (&A2l[0][0])[i] = 0; }
    __syncthreads();
    {
        float v = x[((size_t)(bg * 32 + urow) * T_STEPS + 0) * 16 + ucol];
        unsigned short h = f2bf(v);
        A2h[urow][256 + ucol] = h;
        A2l[urow][256 + ucol] = f2bf(v - bf2f(h));
    }
    __syncthreads();

    float c1 = 0.f, c2 = 0.f;

#define AFRAG(AR, R, B) (*(const short8*)&AR[R][(B) * 32 + quad * 8])

    for (int t = 0; t <= T_STEPS; t++) {   // 366 bodies
        const int p = t & 1;

        // ================= merged GEMM phase =================
        float4_ a10 = {0.f,0.f,0.f,0.f}, a11 = {0.f,0.f,0.f,0.f};
        float4_ a20 = {0.f,0.f,0.f,0.f}, a21 = {0.f,0.f,0.f,0.f};

        if (kh == 0) {
#pragma unroll
            for (int b = 0; b < 8; b++) {
                short8 ah0 = AFRAG(A2h, r16, b),      al0 = AFRAG(A2l, r16, b);
                short8 ah1 = AFRAG(A2h, r16 + 16, b), al1 = AFRAG(A2l, r16 + 16, b);
                if (b < 5) {
                    a10 = MFMA16(ah0, W1H[b], a10);  a11 = MFMA16(ah1, W1H[b], a11);
                    a10 = MFMA16(al0, W1H[b], a10);  a11 = MFMA16(al1, W1H[b], a11);
                    a10 = MFMA16(ah0, W1L[b], a10);  a11 = MFMA16(ah1, W1L[b], a11);
                }
                a20 = MFMA16(ah0, W2H[b], a20);  a21 = MFMA16(ah1, W2H[b], a21);
                a20 = MFMA16(al0, W2H[b], a20);  a21 = MFMA16(al1, W2H[b], a21);
                a20 = MFMA16(ah0, W2L[b], a20);  a21 = MFMA16(ah1, W2L[b], a21);
            }
        } else {
#pragma unroll
            for (int b = 5; b <= 8; b++) {   // P1 blocks 5..8 (8 = x)
                short8 ah0 = AFRAG(A2h, r16, b),      al0 = AFRAG(A2l, r16, b);
                short8 ah1 = AFRAG(A2h, r16 + 16, b), al1 = AFRAG(A2l, r16 + 16, b);
                a10 = MFMA16(ah0, W1H[b - 5], a10);  a11 = MFMA16(ah1, W1H[b - 5], a11);
                a10 = MFMA16(al0, W1H[b - 5], a10);  a11 = MFMA16(al1, W1H[b - 5], a11);
                a10 = MFMA16(ah0, W1L[b - 5], a10);  a11 = MFMA16(ah1, W1L[b - 5], a11);
            }
#pragma unroll
            for (int b = 9; b <= 16; b++) {  // P2 blocks 9..16 (h2)
                short8 ah0 = AFRAG(A2h, r16, b),      al0 = AFRAG(A2l, r16, b);
                short8 ah1 = AFRAG(A2h, r16 + 16, b), al1 = AFRAG(A2l, r16 + 16, b);
                a20 = MFMA16(ah0, W2H[b - 9], a20);  a21 = MFMA16(ah1, W2H[b - 9], a21);
                a20 = MFMA16(al0, W2H[b - 9], a20);  a21 = MFMA16(al1, W2H[b - 9], a21);
                a20 = MFMA16(ah0, W2L[b - 9], a20);  a21 = MFMA16(ah1, W2L[b - 9], a21);
            }
        }

#pragma unroll
        for (int rr = 0; rr < 4; rr++) {
            zb1[kh][quad * 4 + rr][g][r16]      = a10[rr];
            zb1[kh][quad * 4 + rr + 16][g][r16] = a11[rr];
            zb2[kh][quad * 4 + rr][g][r16]      = a20[rr];
            zb2[kh][quad * 4 + rr + 16][g][r16] = a21[rr];
        }
        __syncthreads();   // B1: zb ready; all A reads done

        // ---- update h1_t (layer 1) ----
        {
            float zi = zb1[0][urow][0][ucol] + zb1[1][urow][0][ucol] + bi1[0];
            float zf = zb1[0][urow][1][ucol] + zb1[1][urow][1][ucol] + bi1[1];
            float zg = zb1[0][urow][2][ucol] + zb1[1][urow][2][ucol] + bi1[2];
            float zo = zb1[0][urow][3][ucol] + zb1[1][urow][3][ucol] + bi1[3];
            c1 = sigm(zf) * c1 + sigm(zi) * tanh_(zg);
            float h = sigm(zo) * tanh_(c1);
            size_t o = (((size_t)p * 16 + bg) * 32 + urow) * 256 + colg;
            __hip_atomic_store(&hb1[o], packhl(h), __ATOMIC_RELAXED, __HIP_MEMORY_SCOPE_AGENT);
        }
        // ---- update h2_{t-1} (layer 2, retimed) ----
        {
            float zi = zb2[0][urow][0][ucol] + zb2[1][urow][0][ucol] + bi2[0];
            float zf = zb2[0][urow][1][ucol] + zb2[1][urow][1][ucol] + bi2[1];
            float zg = zb2[0][urow][2][ucol] + zb2[1][urow][2][ucol] + bi2[2];
            float zo = zb2[0][urow][3][ucol] + zb2[1][urow][3][ucol] + bi2[3];
            float nc2 = sigm(zf) * c2 + sigm(zi) * tanh_(zg);
            float h = sigm(zo) * tanh_(nc2);
            if (t == 0) { nc2 = 0.f; h = 0.f; }   // h2_{-1} must stay 0
            c2 = nc2;
            size_t o = (((size_t)(1 - p) * 16 + bg) * 32 + urow) * 256 + colg;
            __hip_atomic_store(&hb2[o], packhl(h), __ATOMIC_RELAXED, __HIP_MEMORY_SCOPE_AGENT);
        }
        __syncthreads();   // B2: publishes drained (vmcnt 0 at barrier)

        if (tid == 0)
            __hip_atomic_store(&myprog[ns], (u32)(t + 1),
                               __ATOMIC_RELAXED, __HIP_MEMORY_SCOPE_AGENT);

        // ---- prefetch x_{t+1} into A block 8 (own LDS; safe post-B1) ----
        {
            int tn = (t + 1 <= T_STEPS - 1) ? t + 1 : T_STEPS - 1;
            float v = x[((size_t)(bg * 32 + urow) * T_STEPS + tn) * 16 + ucol];
            unsigned short h = f2bf(v);
            A2h[urow][256 + ucol] = h;
            A2l[urow][256 + ucol] = f2bf(v - bf2f(h));
        }

        // ---- poll peers (all threads; gates own restage) ----
        {
            u32 tgt = (u32)(t + 1);
            while (__hip_atomic_load(&myprog[tid & 15], __ATOMIC_RELAXED,
                                     __HIP_MEMORY_SCOPE_AGENT) < tgt) {}
        }

        // ---- restage A: h1_t (slot p) -> cols 0..255; h2_{t-1} (slot 1-p) -> 288..543
        {
            const u32* s1 = hb1 + (((size_t)p * 16 + bg) * 32 + urow) * 256 + ucol * 16;
            const u32* s2 = hb2 + (((size_t)(1 - p) * 16 + bg) * 32 + urow) * 256 + ucol * 16;
            stage16p(s1, &A2h[urow][ucol * 16],       &A2l[urow][ucol * 16]);
            stage16p(s2, &A2h[urow][288 + ucol * 16], &A2l[urow][288 + ucol * 16]);
        }
        __syncthreads();   // B3: A ready for next body
    }

    // ---- head (ns==0): out[b] = h2_364 . Wlin + blin ; slot (365-1)&1 = 0 ----
    if (ns != 0) return;
    {
        int row = tid >> 4, seg = tid & 15;
        const u32* src = hb2 + ((size_t)bg * 32 + row) * 256 + seg * 16;   // slot 0
        float s = 0.f;
#pragma unroll
        for (int j = 0; j < 16; j++) {
            u32 v = __hip_atomic_load(&src[j], __ATOMIC_RELAXED, __HIP_MEMORY_SCOPE_AGENT);
            s += (bf2f((unsigned short)(v >> 16)) + bf2f((unsigned short)v)) * Wlin[seg * 16 + j];
        }
        hp[row][seg] = s;
    }
    __syncthreads();
    if (tid < 32) {
        float s = 0.f;
#pragma unroll
        for (int j = 0; j < 16; j++) s += hp[tid][j];
        out[bg * 32 + tid] = s + blin[0];
    }
}

extern "C" void kernel_launch(void* const* d_in, const int* in_sizes, int n_in,
                              void* d_out, int out_size, void* d_ws, size_t ws_size,
                              hipStream_t stream) {
    const float* x    = (const float*)d_in[0];
    const float* Wih1 = (const float*)d_in[1];
    const float* Whh1 = (const float*)d_in[2];
    const float* bih1 = (const float*)d_in[3];
    const float* bhh1 = (const float*)d_in[4];
    const float* Wih2 = (const float*)d_in[5];
    const float* Whh2 = (const float*)d_in[6];
    const float* bih2 = (const float*)d_in[7];
    const float* bhh2 = (const float*)d_in[8];
    const float* Wlin = (const float*)d_in[9];
    const float* blin = (const float*)d_in[10];
    float* out = (float*)d_out;

    char* pp = (char*)d_ws;
    unsigned short* w1h = (unsigned short*)pp; pp += (size_t)64 * 9 * 512 * 2;
    unsigned short* w1l = (unsigned short*)pp; pp += (size_t)64 * 9 * 512 * 2;
    unsigned short* w2h = (unsigned short*)pp; pp += (size_t)64 * 16 * 512 * 2;
    unsigned short* w2l = (unsigned short*)pp; pp += (size_t)64 * 16 * 512 * 2;
    float* bias1 = (float*)pp; pp += 1024 * 4;
    float* bias2 = (float*)pp; pp += 1024 * 4;
    char* zero_base = pp;
    u32* hb1 = (u32*)pp; pp += (size_t)2 * 16 * 32 * 256 * 4;   // 1 MB
    u32* hb2 = (u32*)pp; pp += (size_t)2 * 16 * 32 * 256 * 4;   // 1 MB
    u32* prog = (u32*)pp; pp += 16 * 16 * 4;
    size_t zero_bytes = (size_t)(pp - zero_base);

    hipMemsetAsync(zero_base, 0, zero_bytes, stream);
    prep_w<<<64, 256, 0, stream>>>(Wih1, Whh1, bih1, bhh1, Wih2, Whh2, bih2, bhh2,
                                   w1h, w1l, w2h, w2l, bias1, bias2);
    lstm_main<<<256, 512, 0, stream>>>(x, w1h, w1l, w2h, w2l, bias1, bias2,
                                       hb1, hb2, prog, Wlin, blin, out);
}